// Round 4
// baseline (158.526 us; speedup 1.0000x reference)
//
#include <hip/hip_runtime.h>
#include <hip/hip_bf16.h>
#include <math.h>

// Problem constants (from reference)
#define B_ROWS 4096
#define C_ROWS 2048
#define D_DIM  2048
#define NUM 2
#define MAX_ITER 15
#define NEAREST 3
#define MARGIN 1.0f

typedef __bf16 bf16_t;
typedef bf16_t bf16x8 __attribute__((ext_vector_type(8)));
typedef float f32x4 __attribute__((ext_vector_type(4)));
typedef float f32x16 __attribute__((ext_vector_type(16)));
typedef int i32x4 __attribute__((ext_vector_type(4)));
typedef int i32x8 __attribute__((ext_vector_type(8)));   // 32 fp8 bytes = scaled-MFMA fragment
typedef unsigned char u8;

// ---------------------------------------------------------------------------
// conv: one wave per row, f32 -> fp8 e4m3 (HW cvt_pk, OCP-native on gfx950)
// + row sumsq (exact, from f32) via shuffle. Verified R13/R14: absmax 0.0.
// Rows [0,4096) = feature, [4096,6144) = centers. 4 waves/block.
// Block 0 zero-inits out (select accumulates onto it; stream order).
// ---------------------------------------------------------------------------
__global__ __launch_bounds__(256) void conv_rows(const float* __restrict__ F,
                                                 const float* __restrict__ Cn,
                                                 u8* __restrict__ Fq,
                                                 u8* __restrict__ Cq,
                                                 float* __restrict__ f2,
                                                 float* __restrict__ c2,
                                                 float* __restrict__ out) {
    if (blockIdx.x == 0 && threadIdx.x == 0) out[0] = 0.0f;
    int wave = threadIdx.x >> 6;
    int lane = threadIdx.x & 63;
    int row = blockIdx.x * 4 + wave;          // 0..6143
    const float* p; u8* q; float* sq; int r;
    if (row < B_ROWS) {
        r = row; p = F + (size_t)r * D_DIM; q = Fq + (size_t)r * D_DIM; sq = f2;
    } else {
        r = row - B_ROWS; p = Cn + (size_t)r * D_DIM; q = Cq + (size_t)r * D_DIM; sq = c2;
    }
    float s = 0.0f;
    #pragma unroll
    for (int it = 0; it < 4; ++it) {
        int k = (it * 64 + lane) * 8;         // 8 consecutive floats per lane
        float4 v0 = *(const float4*)(p + k);
        float4 v1 = *(const float4*)(p + k + 4);
        s += v0.x * v0.x + v0.y * v0.y + v0.z * v0.z + v0.w * v0.w;
        s += v1.x * v1.x + v1.y * v1.y + v1.z * v1.z + v1.w * v1.w;
        int lo = __builtin_amdgcn_cvt_pk_fp8_f32(v0.x, v0.y, 0, 0);
        lo     = __builtin_amdgcn_cvt_pk_fp8_f32(v0.z, v0.w, lo, 1);
        int hi = __builtin_amdgcn_cvt_pk_fp8_f32(v1.x, v1.y, 0, 0);
        hi     = __builtin_amdgcn_cvt_pk_fp8_f32(v1.z, v1.w, hi, 1);
        int2 st; st.x = lo; st.y = hi;
        *(int2*)(q + k) = st;                 // 8 bytes, coalesced
    }
    #pragma unroll
    for (int off = 32; off >= 1; off >>= 1) s += __shfl_down(s, off);
    if (lane == 0) sq[r] = s;
}

// ---------------------------------------------------------------------------
// gemm_d2_breg: fp8 MX-scaled distance GEMM, 128x128 tile, 768 blocks
// (3 blocks/CU, 12 waves/CU), 4 waves of 64x64 (2x2 of 32x32 frags),
// MFMA 32x32x64 f8f6f4.
//
// R3 POST-MORTEM (measured): R14 (drain-0) == p3 (counted vmcnt) == ~38us
// -> stage-landing latency is NOT the bottleneck; the LDS data port is
// (reads 96KB + stage-writes 48KB per CU-panel ~= 2000 cyc vs MFMA 825).
// THIS VERSION: B never touches LDS. Each lane's B-fragment is 32
// contiguous bytes of a Cq row -> loaded global->register directly
// (row bn+wn+(lane&31), bytes p*64+(lane>>5)*32; 2 lanes consume each
// 64B line fully; Cq is 4MB, L2-hot with 48x reuse). LDS-port load
// halves; B issue moves to the underloaded VMEM pipe.
//
// A stays in LDS, triple-buffered BK=64 panels (3 x 8KB = 24KB):
// [128 rows][64B], 16B chunk c of row r at slot c ^ ((r>>1)&3) (verified
// R14 swizzle); staged via global_load_lds with inverse swizzle on the
// per-lane GLOBAL source. Read: lane holds row l&31, k-bytes (l>>5)*32
// via two ds_read_b128 at swizzled slots.
//
// Schedule (per panel p): STAGE_A(p+2) [2 GLD] ; sched_barrier(0) ;
// LOADB(p+1)->regs [2x 32B] ; vmcnt(10) ; ds_read A(p) ; 4 MFMA ; barrier.
// Safety proof: sched_barrier pins GLD-before-LOADB per iter; A(p) has
// >=16 newer VMEM items at iter p's vmcnt point, so vmcnt(10) (leave
// newest 10) always drains A(p) under any legal reordering; B-register
// deps are compiler-waited; one barrier/panel protects buffer reuse.
// MEASURED PITFALLS (do not revisit): R5 128B-row banking w/o swizzle;
// R7 nonzero imm offset on global_load_lds; R11 per-lane ROW scatter;
// R13 unswizzled rows; R2-8ph 1-block/CU lockstep (45us, MfmaUtil 20%);
// R3 counted-vmcnt triple-buffer null (stage latency not the bound).
//   Out[m][n] = bf16( a2[m] + c2[n] - 2 * sum_k A[m][k]*Cb[n][k] )
// ---------------------------------------------------------------------------
__global__ __launch_bounds__(256, 3) void gemm_d2_breg(const u8* __restrict__ Fq,
                                                       const u8* __restrict__ Cq,
                                                       const float* __restrict__ f2,
                                                       const float* __restrict__ c2,
                                                       bf16_t* __restrict__ Dfc,
                                                       bf16_t* __restrict__ Dcc) {
    __shared__ __align__(16) u8 As[3][128 * 64];   // 24 KiB total

    const int tid  = threadIdx.x;
    const int wave = tid >> 6;
    const int lane = tid & 63;

    const int by = blockIdx.y;
    const u8* A; const float* a2v; bf16_t* Out; int bm;
    if (by < B_ROWS / 128) { A = Fq; a2v = f2; Out = Dfc; bm = by * 128; }
    else { A = Cq; a2v = c2; Out = Dcc; bm = (by - B_ROWS / 128) * 128; }
    const int bn = blockIdx.x * 128;
    const int N = C_ROWS, K = D_DIM;

    const int wmL = (wave >> 1) * 64;     // 2x2 wave grid, 64x64 per wave
    const int wnL = (wave & 1) * 64;

    // A staging constants: thread t -> row g*64 + wave*16 + (lane>>2),
    // slot lane&3, source chunk (lane&3)^((lane>>3)&3) == slot^((row>>1)&3)
    const int kbyt  = ((lane & 3) ^ ((lane >> 3) & 3)) * 16;
    const int wbase = wave * 1024;                      // wave-uniform LDS base part
    const u8* gA = A + (size_t)(bm + wave * 16 + (lane >> 2)) * K + kbyt;

    // A read constants: m31 = row-in-frag, h = k-half, swr = row swizzle
    const int m31 = lane & 31;
    const int h   = lane >> 5;
    const int swr = (m31 >> 1) & 3;
    const int sl0 = ((h * 2    ) ^ swr) * 16;
    const int sl1 = ((h * 2 + 1) ^ swr) * 16;

    // B direct-from-global: lane's fragment = 32 contiguous bytes of its row
    const u8* gB0 = Cq + (size_t)(bn + wnL + m31) * K + h * 32;
    const u8* gB1 = gB0 + (size_t)32 * K;

    f32x16 acc[2][2] = {};
    i32x8 breg[2][2];                      // [parity][frag], compile-time indexed

#define GLD(dst, src)                                                          \
    __builtin_amdgcn_global_load_lds(                                          \
        (const __attribute__((address_space(1))) void*)(src),                  \
        (__attribute__((address_space(3))) void*)(dst), 16, 0, 0)

#define STAGE_A(q, p)                                                          \
    do {                                                                       \
        GLD(&As[q][0 * 4096 + wbase], gA + (size_t)0 * 64 * K + (p) * 64);     \
        GLD(&As[q][1 * 4096 + wbase], gA + (size_t)1 * 64 * K + (p) * 64);     \
    } while (0)

#define LOADB(s, p)                                                            \
    do {                                                                       \
        breg[s][0] = *(const i32x8*)(gB0 + (p) * 64);                          \
        breg[s][1] = *(const i32x8*)(gB1 + (p) * 64);                          \
    } while (0)

    auto rd = [&](const u8* buf, int rowbase) -> i32x8 {
        const u8* pp = buf + rowbase * 64;
        i32x4 lo = *(const i32x4*)(pp + sl0);
        i32x4 hi = *(const i32x4*)(pp + sl1);
        i32x8 r;
        r[0] = lo.x; r[1] = lo.y; r[2] = lo.z; r[3] = lo.w;
        r[4] = hi.x; r[5] = hi.y; r[6] = hi.z; r[7] = hi.w;
        return r;
    };

#define BAR() __builtin_amdgcn_s_barrier()
#define WAITV(n) asm volatile("s_waitcnt vmcnt(" #n ")" ::: "memory")
#define SCHED() __builtin_amdgcn_sched_barrier(0)

    // ---- prologue: A(0),A(1) staged; B(0) in regs; land A(0); barrier ----
    STAGE_A(0, 0);
    STAGE_A(1, 1);
    SCHED();
    LOADB(0, 0);
    WAITV(6);            // queue [A0(2),A1(2),B0(4)] -> drains exactly A0
    BAR();

    // ---- 32 panels, fully unrolled (buffer %3 and parity &1 fold) ----
    #pragma unroll
    for (int p = 0; p < 32; ++p) {
        if (p + 2 < 32) STAGE_A((p + 2) % 3, p + 2);
        SCHED();         // pins GLD-before-LOADB issue order (FIFO proof)
        if (p + 1 < 32) LOADB((p + 1) & 1, p + 1);
        if (p < 31) { WAITV(10); }   // drains A(p) (>=16 newer items), keeps
        else        { WAITV(4);  }   // B(p)/A(p+1..)/B(p+1) in flight
        {
            i32x8 a0 = rd(As[p % 3], wmL + m31);
            i32x8 a1 = rd(As[p % 3], wmL + 32 + m31);
            __builtin_amdgcn_s_setprio(1);
            acc[0][0] = __builtin_amdgcn_mfma_scale_f32_32x32x64_f8f6f4(
                a0, breg[p & 1][0], acc[0][0], 0, 0, 0, 0x7F7F7F7F, 0, 0x7F7F7F7F);
            acc[0][1] = __builtin_amdgcn_mfma_scale_f32_32x32x64_f8f6f4(
                a0, breg[p & 1][1], acc[0][1], 0, 0, 0, 0x7F7F7F7F, 0, 0x7F7F7F7F);
            acc[1][0] = __builtin_amdgcn_mfma_scale_f32_32x32x64_f8f6f4(
                a1, breg[p & 1][0], acc[1][0], 0, 0, 0, 0x7F7F7F7F, 0, 0x7F7F7F7F);
            acc[1][1] = __builtin_amdgcn_mfma_scale_f32_32x32x64_f8f6f4(
                a1, breg[p & 1][1], acc[1][1], 0, 0, 0, 0x7F7F7F7F, 0, 0x7F7F7F7F);
            __builtin_amdgcn_s_setprio(0);
        }
        if (p < 31) BAR();
    }

    // ---- epilogue: d2 = a2[m] + c2[n] - 2*dot, stored bf16 ----
    // 32x32 C/D: col = lane&31, row = (reg&3) + 8*(reg>>2) + 4*(lane>>5)
    #pragma unroll
    for (int i = 0; i < 2; ++i) {
        #pragma unroll
        for (int r = 0; r < 16; ++r) {
            int m = bm + wmL + i * 32 + (r & 3) + 8 * (r >> 2) + 4 * h;
            float am = a2v[m];
            #pragma unroll
            for (int j = 0; j < 2; ++j) {
                int n = bn + wnL + j * 32 + m31;
                Out[(size_t)m * N + n] = (bf16_t)(am + c2[n] - 2.0f * acc[i][j][r]);
            }
        }
    }
#undef GLD
#undef STAGE_A
#undef LOADB
#undef BAR
#undef WAITV
#undef SCHED
}

// ---------------------------------------------------------------------------
// select v3: bf16 distance rows, vectorized 16B loads.
// Iterative argmin w/ exclusion over Dfc row; on-demand trust from Dcc:
//   label in near3[sel]  <=>  #{ j : (Dcc[sel][j], j) <lex (Dcc[sel][label],
//   label) } < NEAREST   (stable argsort -> lexicographic order)
// Ownership: lane l, group g, sub e: n = g*512 + l*8 + e; excl bit g*8+e.
// 4 waves/block, one row per wave; one atomicAdd per block onto out.
// ---------------------------------------------------------------------------
__global__ __launch_bounds__(256) void select_kernel(const bf16_t* __restrict__ Dfc,
                                                     const bf16_t* __restrict__ Dcc,
                                                     float* __restrict__ out, int C) {
    int wave = threadIdx.x >> 6, lane = threadIdx.x & 63;
    int b = blockIdx.x * 4 + wave;
    int label = b / NUM;
    const bf16_t* row = Dfc + (size_t)b * C;

    float vals[32];
    #pragma unroll
    for (int g = 0; g < 4; ++g) {
        bf16x8 v = *(const bf16x8*)(row + g * 512 + lane * 8);
        #pragma unroll
        for (int e = 0; e < 8; ++e) {
            int n = g * 512 + lane * 8 + e;
            float f = (float)v[e];
            vals[g * 8 + e] = (n == label) ? INFINITY : f;
        }
    }

    unsigned int excl = 0;
    float min_diff = 0.0f;
    int found = 0;
    for (int it = 0; it < MAX_ITER; ++it) {
        float bestv = INFINITY; int bestidx = 0x7fffffff;
        #pragma unroll
        for (int g = 0; g < 4; ++g)
            #pragma unroll
            for (int e = 0; e < 8; ++e) {
                int bit = g * 8 + e;
                if (excl & (1u << bit)) continue;
                float v = vals[bit];
                int idx = g * 512 + lane * 8 + e;
                if (v < bestv || (v == bestv && idx < bestidx)) { bestv = v; bestidx = idx; }
            }
        for (int off = 32; off >= 1; off >>= 1) {
            float ov = __shfl_down(bestv, off); int oi = __shfl_down(bestidx, off);
            if (ov < bestv || (ov == bestv && oi < bestidx)) { bestv = ov; bestidx = oi; }
        }
        int sel = __shfl(bestidx, 0);
        float selv = __shfl(bestv, 0);

        // --- on-demand trust: count lex-smaller entries of Dcc row sel ---
        const bf16_t* crow = Dcc + (size_t)sel * C;
        float dl = (float)crow[label];          // uniform address: broadcast
        int cnt = 0;
        #pragma unroll
        for (int g = 0; g < 4; ++g) {
            bf16x8 v = *(const bf16x8*)(crow + g * 512 + lane * 8);
            #pragma unroll
            for (int e = 0; e < 8; ++e) {
                int idx = g * 512 + lane * 8 + e;
                float f = (float)v[e];
                cnt += (f < dl || (f == dl && idx < label)) ? 1 : 0;
            }
        }
        #pragma unroll
        for (int off = 32; off >= 1; off >>= 1) cnt += __shfl_down(cnt, off);
        cnt = __shfl(cnt, 0);
        bool trusted = (cnt >= NEAREST);

        if (trusted) { min_diff = sqrtf(fmaxf(selv, 0.0f)); found = 1; break; }
        if (((sel >> 3) & 63) == lane) excl |= 1u << (((sel >> 9) << 3) | (sel & 7));
    }
    __shared__ float hs[4];
    if (lane == 0) {
        float same = sqrtf(fmaxf((float)row[label], 0.0f));
        float md = found ? min_diff : 0.0f;
        hs[wave] = fmaxf(MARGIN + same - md, 0.0f);
    }
    __syncthreads();
    if (threadIdx.x == 0)
        atomicAdd(out, (hs[0] + hs[1] + hs[2] + hs[3]) * (1.0f / (float)B_ROWS));
}

// ---------------------------------------------------------------------------
extern "C" void kernel_launch(void* const* d_in, const int* in_sizes, int n_in,
                              void* d_out, int out_size, void* d_ws, size_t ws_size,
                              hipStream_t stream) {
    const float* feature = (const float*)d_in[0];  // 4096 x 2048
    const float* centers = (const float*)d_in[1];  // 2048 x 2048
    float* out = (float*)d_out;                    // scalar

    // Workspace layout (distances bf16, quantized inputs fp8)
    bf16_t* Dfc  = (bf16_t*)d_ws;                            // 4096*2048 bf16
    bf16_t* Dcc  = Dfc + (size_t)B_ROWS * C_ROWS;            // 2048*2048 bf16
    u8*     Fq   = (u8*)(Dcc + (size_t)C_ROWS * C_ROWS);     // 4096*2048 fp8
    u8*     Cq   = Fq + (size_t)B_ROWS * D_DIM;              // 2048*2048 fp8
    float*  f2   = (float*)(Cq + (size_t)C_ROWS * D_DIM);    // 4096
    float*  c2   = f2 + B_ROWS;                              // 2048

    conv_rows<<<(B_ROWS + C_ROWS) / 4, 256, 0, stream>>>(feature, centers, Fq, Cq,
                                                         f2, c2, out);

    // Both distance matrices in one dispatch: grid (16, 32+16) = 768 blocks,
    // 256 threads (4 waves), 24 KiB LDS -> 3 blocks/CU resident.
    gemm_d2_breg<<<dim3(C_ROWS / 128, B_ROWS / 128 + C_ROWS / 128), 256, 0, stream>>>(
        Fq, Cq, f2, c2, Dfc, Dcc);

    // select with on-demand trust (reads Dcc directly; no near3 dispatch).
    select_kernel<<<B_ROWS / 4, 256, 0, stream>>>(Dfc, Dcc, out, C_ROWS);
}